// Round 1
// 2354.283 us; speedup vs baseline: 1.1097x; 1.1097x over previous
//
#include <hip/hip_runtime.h>
#include <cstdint>
#include <cstddef>

// Decoder_55654186222328 — MI355X, R9: swapped-operand attention, in-register P.
// R8 post-mortem: HBM at 0.17% peak -> not memory-bound. Bottleneck was P4's
// per-chunk P round-trip through LDS: 16 ds_write_b8 with ~16-way bank
// conflicts (SQ_LDS_BANK_CONFLICT 1.79e8) + full lgkmcnt(0) drain + conflicted
// re-reads, at 2 waves/SIMD occupancy.
// R9 fixes:
//  * Scores computed operand-swapped: S^T = mfma(K_frag, Q_frag) (fragment
//    loads identical, args swapped). Lane then holds P[a=l16][m=quad*4+r] --
//    exactly its PV B-fragment bytes under permutation pi(8q+j)=4q+j|16+4q+j-4.
//    pi is baked into V8 storage (kv_kernel), so PV = mfma(V_frag, P_regs)
//    producing O^T. ZERO LDS traffic for P; no drain; O^T packs to b64 writes.
//  * Mask folded into spare k=16 MFMA slot: K-side flag fp8 1.0 (masked) x
//    Q-side fp8 -256 => exp2f(S-256)=0 exactly. No mask ops in inner loop
//    (per-lane 32-bit flag word precomputed once).
//  * P7 parallelized across all 512 threads (8 threads/output + shfl reduce).
// 256 blocks (128 b x 2 agent halves of 32) x 512 threads, 1 block/CU,
// LDS 162560 B.

typedef short short8 __attribute__((ext_vector_type(8)));
typedef float f32x4 __attribute__((ext_vector_type(4)));

#define LOG2E 1.4426950408889634f
#define QSCALE 0.36067376022224085f /* log2(e)/4 */

__device__ __forceinline__ unsigned short f2bf(float f) {
  union { float f; unsigned int u; } v; v.f = f;
  unsigned int u = v.u;
  return (unsigned short)((u + 0x7fffu + ((u >> 16) & 1u)) >> 16);  // RNE
}
__device__ __forceinline__ float sigm(float x) {
  return 1.f / (1.f + exp2f(-LOG2E * x));
}
__device__ __forceinline__ float tanh_f(float x) {
  return 1.f - 2.f / (1.f + exp2f(2.f * LOG2E * x));
}
__device__ __forceinline__ f32x4 splat4(float v) { f32x4 r = {v, v, v, v}; return r; }
__device__ __forceinline__ unsigned char f2fp8(float x) {
  return (unsigned char)__builtin_amdgcn_cvt_pk_fp8_f32(x, x, 0, false);
}
__device__ __forceinline__ f32x4 mfma_fp8(long a, long b, f32x4 c) {
  return __builtin_amdgcn_mfma_f32_16x16x32_fp8_fp8(a, b, c, 0, 0, 0);
}

// ---------------------------------------------------------------- convert ----
__global__ __launch_bounds__(256) void convert_kernel(
    const float* __restrict__ wq, const float* __restrict__ wo,
    const float* __restrict__ w2, const float* __restrict__ w3,
    const float* __restrict__ wih, const float* __restrict__ whh,
    const float* __restrict__ bih, const float* __restrict__ bhh,
    const float* __restrict__ bq,
    unsigned short* __restrict__ WQ, unsigned short* __restrict__ WO,
    unsigned short* __restrict__ W2, unsigned short* __restrict__ W3,
    unsigned short* __restrict__ WIH, unsigned short* __restrict__ WHH,
    float* __restrict__ B4, float* __restrict__ BQS) {
  int i = blockIdx.x * 256 + threadIdx.x;
  if (i >= 180864) return;
  if (i < 16384)       WQ[i] = f2bf(wq[i] * QSCALE);
  else if (i < 32768)  WO[i - 16384] = f2bf(wo[i - 16384]);
  else if (i < 40960)  W2[i - 32768] = f2bf(w2[i - 32768]);
  else if (i < 49152)  W3[i - 40960] = f2bf(w3[i - 40960]);
  else if (i < 114688) WIH[i - 49152] = f2bf(wih[i - 49152]);
  else if (i < 180224) WHH[i - 114688] = f2bf(whh[i - 114688]);
  else if (i < 180736) { int j = i - 180224; B4[j] = bih[j] + bhh[j]; }
  else                 { int j = i - 180736; BQS[j] = bq[j] * QSCALE; }
}

// ---------------------------------------------------------------- K/V --------
// K8[b][m][128] fp8; V8[b][d][512] fp8 (transposed, m-permuted within each
// 32-token chunk: byte slot s holds token pi(s), pi(8q+j)=4q+j (j<4) else
// 16+4q+(j-4), matching the decoder's in-register P fragment ordering).
// grid 1024 = 128 b x 8 chunks.
__global__ __launch_bounds__(256) void kv_kernel(
    const float* __restrict__ emb, const float* __restrict__ wk,
    const float* __restrict__ bk, const float* __restrict__ wv,
    const float* __restrict__ bv,
    unsigned char* __restrict__ K8, unsigned char* __restrict__ V8) {
  extern __shared__ char smem[];
  float* s_e = (float*)smem;            // [64][129]
  float* s_w = (float*)(smem + 33024);  // [128][129]
  const int tid = threadIdx.x;
  const int b = blockIdx.x >> 3;
  const int m0 = (blockIdx.x & 7) * 64;

  for (int i = tid; i < 8192; i += 256) {
    int row = i >> 7, col = i & 127;
    s_e[row * 129 + col] = emb[(size_t)(b * 512 + m0 + row) * 128 + col];
  }
  for (int i = tid; i < 16384; i += 256) {
    int row = i >> 7, col = i & 127;
    s_w[row * 129 + col] = wk[i];
  }
  __syncthreads();
  {  // K rows -> fp8
    const int dg = tid & 31, rg = tid >> 5;
    float acc[8][4];
#pragma unroll
    for (int rr = 0; rr < 8; ++rr)
#pragma unroll
      for (int j = 0; j < 4; ++j) acc[rr][j] = 0.f;
    for (int k = 0; k < 128; ++k) {
      float e[8];
#pragma unroll
      for (int rr = 0; rr < 8; ++rr) e[rr] = s_e[(rg * 8 + rr) * 129 + k];
#pragma unroll
      for (int j = 0; j < 4; ++j) {
        float w = s_w[(dg * 4 + j) * 129 + k];
#pragma unroll
        for (int rr = 0; rr < 8; ++rr) acc[rr][j] = fmaf(e[rr], w, acc[rr][j]);
      }
    }
#pragma unroll
    for (int rr = 0; rr < 8; ++rr)
#pragma unroll
      for (int j = 0; j < 4; ++j) {
        int d = dg * 4 + j;
        K8[(size_t)(b * 512 + m0 + rg * 8 + rr) * 128 + d] = f2fp8(acc[rr][j] + bk[d]);
      }
  }
  __syncthreads();
  for (int i = tid; i < 16384; i += 256) {
    int row = i >> 7, col = i & 127;
    s_w[row * 129 + col] = wv[i];
  }
  __syncthreads();
  {  // V transposed + m-permuted -> fp8
    const int r = tid & 63, dg = tid >> 6;
    float acc[32];
#pragma unroll
    for (int j = 0; j < 32; ++j) acc[j] = 0.f;
    for (int k = 0; k < 128; ++k) {
      float e = s_e[r * 129 + k];
#pragma unroll
      for (int j = 0; j < 32; ++j) acc[j] = fmaf(e, s_w[(dg * 32 + j) * 129 + k], acc[j]);
    }
    const int m = m0 + r;
    const int ml = m & 31;
    const int sperm = (ml < 16) ? (((ml >> 2) << 3) | (ml & 3))
                                : ((((ml - 16) >> 2) << 3) | ((ml - 16) & 3) | 4);
    const int mpos = (m & ~31) | sperm;
#pragma unroll
    for (int j = 0; j < 32; ++j) {
      int d = dg * 32 + j;
      V8[(size_t)(b * 128 + d) * 512 + mpos] = f2fp8(acc[j] + bv[d]);
    }
  }
}

// ---------------------------------------------------------------- decoder ----
// grid 256 = 128 b x 2 agent-halves (32 agents). 512 threads = 8 waves.
// LDS (162560 B, 1 block/CU):
//   sK    @0      fp8 [512][128] XOR-swz  65536   (persistent)
//   sV    @65536  fp8 [128][512] XOR-swz  65536   (persistent, transposed+pi)
//   bufA  @131072 u16 [32][136]            8704   (h1 | x)
//   bufB  @139776 u16 [32][136]            8704   (e | o)
//   s_h   @148480 u16 [32][136]            8704
//   zone  @157184 4608: h2 u16 [32][72] then qf8 u8 [32][136] (disjoint lives)
//   state @161792 f32 [64]                  256
//   maskb @162048 u8 [512]                  512
__global__ __launch_bounds__(512, 2) void decoder_kernel(
    const float* __restrict__ cf, const int* __restrict__ cav,
    const float* __restrict__ hid,
    const float* __restrict__ ctx, const int* __restrict__ mav,
    const int* __restrict__ ntp,
    const float* __restrict__ w1, const float* __restrict__ b1,
    const float* __restrict__ b2, const float* __restrict__ b3,
    const float* __restrict__ boP,
    const unsigned char* __restrict__ K8, const unsigned char* __restrict__ V8,
    const unsigned short* __restrict__ WQ, const unsigned short* __restrict__ WO,
    const unsigned short* __restrict__ W2, const unsigned short* __restrict__ W3,
    const unsigned short* __restrict__ WIH, const unsigned short* __restrict__ WHH,
    const float* __restrict__ B4, const float* __restrict__ BQS,
    const float* __restrict__ lnw, const float* __restrict__ lnb,
    float* __restrict__ out) {
  extern __shared__ char smem[];
  unsigned short* s_bufA = (unsigned short*)(smem + 131072);
  unsigned short* s_bufB = (unsigned short*)(smem + 139776);
  unsigned short* s_h = (unsigned short*)(smem + 148480);
  unsigned short* s_h2 = (unsigned short*)(smem + 157184);
  unsigned char* s_qf8 = (unsigned char*)(smem + 157184);
  float* s_state = (float*)(smem + 161792);
  unsigned char* s_maskb = (unsigned char*)(smem + 162048);

  const int tid = threadIdx.x;
  const int wave = tid >> 6;
  const int lane = tid & 63;
  const int quad = lane >> 4;
  const int l16 = lane & 15;

  const int b = blockIdx.x & 127;
  const int a0 = (blockIdx.x >> 7) * 32;
  const int T = *ntp;
  const f32x4 zero4 = {0.f, 0.f, 0.f, 0.f};
  const long kOnes = 0x3838383838383838L;  // fp8 e4m3 1.0 x8

  // ---- preload persistent K/V into LDS with XOR swizzle ----
  {
    const unsigned long long* Kg = (const unsigned long long*)(K8 + (size_t)b * 65536);
    for (int i = tid; i < 8192; i += 512) {
      int tok = i >> 4, seg = i & 15;
      *(unsigned long long*)(smem + tok * 128 + ((seg * 8) ^ ((tok & 15) * 8))) =
          Kg[(size_t)tok * 16 + seg];
    }
    const unsigned long long* Vg = (const unsigned long long*)(V8 + (size_t)b * 65536);
    for (int i = tid; i < 8192; i += 512) {
      int d = i >> 6, seg = i & 63;
      *(unsigned long long*)(smem + 65536 + d * 512 + ((seg * 8) ^ ((d & 15) * 8))) =
          Vg[(size_t)d * 64 + seg];
    }
  }
  // ---- init ----
  if (tid < 64) {
    int a = tid >> 1, oi = tid & 1;
    s_state[a * 2 + oi] = cf[(size_t)(b * 64 + a0 + a) * 2 + oi];
  }
  s_maskb[tid] = mav[b * 512 + tid] ? 1 : 0;
  {  // h0 (32 agents x 128 -> 8 per thread)
    int idx = tid * 8;
    int a = idx >> 7, n0 = idx & 127;
    const float* hp = hid + (size_t)(b * 64 + a0 + a) * 128 + n0;
    short8 v;
#pragma unroll
    for (int j = 0; j < 8; ++j) v[j] = (short)f2bf(hp[j]);
    *(short8*)(s_h + a * 136 + n0) = v;
  }
  float c_reg[2][4], avl[2][4];
#pragma unroll
  for (int mt = 0; mt < 2; ++mt)
#pragma unroll
    for (int r = 0; r < 4; ++r) {
      int a = mt * 16 + quad * 4 + r;
      c_reg[mt][r] = ctx[(size_t)(b * 64 + a0 + a) * 128 + wave * 16 + l16];
      avl[mt][r] = (cav[b * 64 + a0 + a] != 0) ? 1.f : 0.f;
    }
  __syncthreads();

  // per-lane mask flags: bit i set when token i*16+l16 is NOT available.
  // Used as the k=16 MFMA slot flag (fp8 1.0) against Q-side -256.
  unsigned mflags = 0;
#pragma unroll
  for (int i = 0; i < 32; ++i)
    if (!s_maskb[i * 16 + l16]) mflags |= (1u << i);

#pragma unroll 1
  for (int t = 0; t < T; ++t) {
    // ---- P0: h1 = relu(state @ w1^T + b1) -> bufA ----
    {
      int a = tid >> 4, n0 = (tid & 15) * 8;
      float st0 = s_state[a * 2], st1 = s_state[a * 2 + 1];
      const float* wp = w1 + n0 * 2;
      const float* bp = b1 + n0;
      short8 v;
#pragma unroll
      for (int j = 0; j < 8; ++j) {
        float x = fmaf(wp[j * 2], st0, fmaf(wp[j * 2 + 1], st1, bp[j]));
        v[j] = (short)f2bf(fmaxf(x, 0.f));
      }
      *(short8*)(s_bufA + a * 136 + n0) = v;
    }
    __syncthreads();

    // ---- P1: h2 = relu(h1 @ w2^T + b2)  M32 N64 K128 -> zone ----
    {
      int mt = wave >> 2, nt = wave & 3;
      f32x4 acc = splat4(b2[nt * 16 + l16]);
#pragma unroll
      for (int kt = 0; kt < 4; ++kt) {
        short8 a8 = *(const short8*)(s_bufA + (mt * 16 + l16) * 136 + kt * 32 + quad * 8);
        short8 b8 = *(const short8*)(W2 + ((nt * 16 + l16) * 128 + kt * 32 + quad * 8));
        acc = __builtin_amdgcn_mfma_f32_16x16x32_bf16(a8, b8, acc, 0, 0, 0);
      }
#pragma unroll
      for (int r = 0; r < 4; ++r)
        s_h2[(mt * 16 + quad * 4 + r) * 72 + nt * 16 + l16] = f2bf(fmaxf(acc[r], 0.f));
    }
    __syncthreads();

    // ---- P2: e = h2 @ w3^T + b3  M32 N128 K64 -> bufB ----
    {
      int nt = wave;
      float bv = b3[nt * 16 + l16];
      short8 b8[2];
#pragma unroll
      for (int kt = 0; kt < 2; ++kt)
        b8[kt] = *(const short8*)(W3 + ((nt * 16 + l16) * 64 + kt * 32 + quad * 8));
#pragma unroll
      for (int mt = 0; mt < 2; ++mt) {
        f32x4 acc = splat4(bv);
#pragma unroll
        for (int kt = 0; kt < 2; ++kt) {
          short8 a8 = *(const short8*)(s_h2 + (mt * 16 + l16) * 72 + kt * 32 + quad * 8);
          acc = __builtin_amdgcn_mfma_f32_16x16x32_bf16(a8, b8[kt], acc, 0, 0, 0);
        }
#pragma unroll
        for (int r = 0; r < 4; ++r)
          s_bufB[(mt * 16 + quad * 4 + r) * 136 + nt * 16 + l16] = f2bf(acc[r]);
      }
    }
    __syncthreads();

    // ---- P3: q = e @ wq_s^T + bq_s -> fp8 qf8 (overlays h2; h2 dead) ----
    {
      int nt = wave;
      float bv = BQS[nt * 16 + l16];
      short8 b8[4];
#pragma unroll
      for (int kt = 0; kt < 4; ++kt)
        b8[kt] = *(const short8*)(WQ + ((nt * 16 + l16) * 128 + kt * 32 + quad * 8));
#pragma unroll
      for (int mt = 0; mt < 2; ++mt) {
        f32x4 acc = splat4(bv);
#pragma unroll
        for (int kt = 0; kt < 4; ++kt) {
          short8 a8 = *(const short8*)(s_bufB + (mt * 16 + l16) * 136 + kt * 32 + quad * 8);
          acc = __builtin_amdgcn_mfma_f32_16x16x32_bf16(a8, b8[kt], acc, 0, 0, 0);
        }
#pragma unroll
        for (int r = 0; r < 4; ++r)
          s_qf8[(mt * 16 + quad * 4 + r) * 136 + nt * 16 + l16] = f2fp8(acc[r]);
      }
    }
    __syncthreads();

    // ---- P4: attention — swapped-operand MFMA, P stays in registers ----
    // S^T = mfma(K_frag, Q_frag): lane holds S[a=l16][m=quad*4+r] per nt half.
    // Those 8 values are exactly the lane's PV B-fragment bytes under pi
    // (baked into V8). Mask folded into k=16 slot: K flag 1.0 x Q -256.
    {
      const int h = wave;
      const char* sKb = (const char*)smem;
      const char* sVrow = (const char*)(smem + 65536) + (h * 16 + l16) * 512;
      long qA[2];
#pragma unroll
      for (int mt = 0; mt < 2; ++mt)
        qA[mt] = (quad < 2)
                     ? *(const long*)(s_qf8 + (mt * 16 + l16) * 136 + h * 16 + quad * 8)
                     : (quad == 2 ? 0xF8L : 0L);  // byte0 = fp8 -256
      const int koff = (h * 16 + quad * 8) ^ (l16 * 8);
      f32x4 O[2], L4[2];
      O[0] = zero4; O[1] = zero4; L4[0] = zero4; L4[1] = zero4;
#pragma unroll 2
      for (int c = 0; c < 16; ++c) {
        long vA = *(const long*)(sVrow + ((c * 32 + quad * 8) ^ (l16 * 8)));
        f32x4 S2[2][2];
#pragma unroll
        for (int nt = 0; nt < 2; ++nt) {
          long kB;
          if (quad < 2)
            kB = *(const long*)(sKb + (size_t)(c * 32 + nt * 16 + l16) * 128 + koff);
          else if (quad == 2)
            kB = ((mflags >> (c * 2 + nt)) & 1u) ? 0x38L : 0L;  // fp8 1.0 flag
          else
            kB = 0L;
          S2[nt][0] = mfma_fp8(kB, qA[0], zero4);
          S2[nt][1] = mfma_fp8(kB, qA[1], zero4);
        }
#pragma unroll
        for (int mt = 0; mt < 2; ++mt) {
          unsigned w0 = (unsigned)__builtin_amdgcn_cvt_pk_fp8_f32(
              exp2f(S2[0][mt][0]), exp2f(S2[0][mt][1]), 0, false);
          w0 = (unsigned)__builtin_amdgcn_cvt_pk_fp8_f32(
              exp2f(S2[0][mt][2]), exp2f(S2[0][mt][3]), (int)w0, true);
          unsigned w1 = (unsigned)__builtin_amdgcn_cvt_pk_fp8_f32(
              exp2f(S2[1][mt][0]), exp2f(S2[1][mt][1]), 0, false);
          w1 = (unsigned)__builtin_amdgcn_cvt_pk_fp8_f32(
              exp2f(S2[1][mt][2]), exp2f(S2[1][mt][3]), (int)w1, true);
          long pB = (long)(((unsigned long long)w1 << 32) | (unsigned long long)w0);
          O[mt] = mfma_fp8(vA, pB, O[mt]);     // O^T: rows d-local, cols a
          L4[mt] = mfma_fp8(kOnes, pB, L4[mt]);
        }
      }
      // o -> bufB (e dead); O^T lane layout: d = h*16+quad*4+r, a = mt*16+l16
#pragma unroll
      for (int mt = 0; mt < 2; ++mt) {
        unsigned long long ow = 0;
#pragma unroll
        for (int r = 0; r < 4; ++r)
          ow |= (unsigned long long)f2bf(O[mt][r] / L4[mt][r]) << (16 * r);
        *(unsigned long long*)(s_bufB + (mt * 16 + l16) * 136 + h * 16 + quad * 4) = ow;
      }
    }
    __syncthreads();

    // ---- P5: x = o @ wo^T + bo -> bufA ----
    {
      int nt = wave;
      float bv = boP[nt * 16 + l16];
      short8 b8[4];
#pragma unroll
      for (int kt = 0; kt < 4; ++kt)
        b8[kt] = *(const short8*)(WO + ((nt * 16 + l16) * 128 + kt * 32 + quad * 8));
#pragma unroll
      for (int mt = 0; mt < 2; ++mt) {
        f32x4 acc = splat4(bv);
#pragma unroll
        for (int kt = 0; kt < 4; ++kt) {
          short8 a8 = *(const short8*)(s_bufB + (mt * 16 + l16) * 136 + kt * 32 + quad * 8);
          acc = __builtin_amdgcn_mfma_f32_16x16x32_bf16(a8, b8[kt], acc, 0, 0, 0);
        }
#pragma unroll
        for (int r = 0; r < 4; ++r)
          s_bufA[(mt * 16 + quad * 4 + r) * 136 + nt * 16 + l16] = f2bf(acc[r]);
      }
    }
    __syncthreads();

    // ---- P6: LSTM gates + elementwise ----
    {
      const int ni = wave;
      const int wrow = ni * 16 + l16;
      f32x4 gi[2], gf[2], gg[2], go[2];
#pragma unroll
      for (int mt = 0; mt < 2; ++mt) {
        gi[mt] = splat4(B4[wrow]);
        gf[mt] = splat4(B4[128 + wrow]);
        gg[mt] = splat4(B4[256 + wrow]);
        go[mt] = splat4(B4[384 + wrow]);
      }
#pragma unroll
      for (int kt = 0; kt < 4; ++kt) {
        short8 b_i = *(const short8*)(WIH + ((0 + wrow) * 128 + kt * 32 + quad * 8));
        short8 b_f = *(const short8*)(WIH + ((128 + wrow) * 128 + kt * 32 + quad * 8));
        short8 b_g = *(const short8*)(WIH + ((256 + wrow) * 128 + kt * 32 + quad * 8));
        short8 b_o = *(const short8*)(WIH + ((384 + wrow) * 128 + kt * 32 + quad * 8));
#pragma unroll
        for (int mt = 0; mt < 2; ++mt) {
          short8 a8 = *(const short8*)(s_bufA + (mt * 16 + l16) * 136 + kt * 32 + quad * 8);
          gi[mt] = __builtin_amdgcn_mfma_f32_16x16x32_bf16(a8, b_i, gi[mt], 0, 0, 0);
          gf[mt] = __builtin_amdgcn_mfma_f32_16x16x32_bf16(a8, b_f, gf[mt], 0, 0, 0);
          gg[mt] = __builtin_amdgcn_mfma_f32_16x16x32_bf16(a8, b_g, gg[mt], 0, 0, 0);
          go[mt] = __builtin_amdgcn_mfma_f32_16x16x32_bf16(a8, b_o, go[mt], 0, 0, 0);
        }
      }
#pragma unroll
      for (int kt = 0; kt < 4; ++kt) {
        short8 b_i = *(const short8*)(WHH + ((0 + wrow) * 128 + kt * 32 + quad * 8));
        short8 b_f = *(const short8*)(WHH + ((128 + wrow) * 128 + kt * 32 + quad * 8));
        short8 b_g = *(const short8*)(WHH + ((256 + wrow) * 128 + kt * 32 + quad * 8));
        short8 b_o = *(const short8*)(WHH + ((384 + wrow) * 128 + kt * 32 + quad * 8));
#pragma unroll
        for (int mt = 0; mt < 2; ++mt) {
          short8 a8 = *(const short8*)(s_h + (mt * 16 + l16) * 136 + kt * 32 + quad * 8);
          gi[mt] = __builtin_amdgcn_mfma_f32_16x16x32_bf16(a8, b_i, gi[mt], 0, 0, 0);
          gf[mt] = __builtin_amdgcn_mfma_f32_16x16x32_bf16(a8, b_f, gf[mt], 0, 0, 0);
          gg[mt] = __builtin_amdgcn_mfma_f32_16x16x32_bf16(a8, b_g, gg[mt], 0, 0, 0);
          go[mt] = __builtin_amdgcn_mfma_f32_16x16x32_bf16(a8, b_o, go[mt], 0, 0, 0);
        }
      }
      float hnew[2][4];
#pragma unroll
      for (int mt = 0; mt < 2; ++mt)
#pragma unroll
        for (int r = 0; r < 4; ++r) {
          float iv = sigm(gi[mt][r]);
          float fv = sigm(gf[mt][r]);
          float gv = tanh_f(gg[mt][r]);
          float ov = sigm(go[mt][r]);
          float cn = fmaf(fv, c_reg[mt][r], iv * gv);
          float hv = ov * tanh_f(cn);
          int arow = mt * 16 + quad * 4 + r;
          float av = avl[mt][r];
          union { unsigned int u; float f; } ho;
          ho.u = ((unsigned int)s_h[arow * 136 + ni * 16 + l16]) << 16;
          c_reg[mt][r] = av * cn + (1.f - av) * c_reg[mt][r];
          hnew[mt][r] = av * hv + (1.f - av) * ho.f;
        }
      __syncthreads();  // all h reads (incl. MFMA A-frags) done before overwrite
#pragma unroll
      for (int mt = 0; mt < 2; ++mt)
#pragma unroll
        for (int r = 0; r < 4; ++r) {
          int arow = mt * 16 + quad * 4 + r;
          s_h[arow * 136 + ni * 16 + l16] = f2bf(hnew[mt][r]);
        }
    }
    __syncthreads();

    // ---- P7: state += h @ lin_w^T + lin_b; emit (all 512 threads) ----
    {
      int o = tid >> 3;        // 0..63 = a*2+oi
      int sub = tid & 7;       // 8 threads per output, 16 k each
      int a = o >> 1, oi = o & 1;
      const unsigned short* hp = s_h + a * 136 + sub * 16;
      const float* lw = lnw + oi * 128 + sub * 16;
      short8 h0 = *(const short8*)hp;
      short8 h1 = *(const short8*)(hp + 8);
      float acc = 0.f;
#pragma unroll
      for (int k = 0; k < 8; ++k) {
        union { unsigned int u; float f; } hv;
        hv.u = ((unsigned int)(unsigned short)h0[k]) << 16;
        acc = fmaf(hv.f, lw[k], acc);
      }
#pragma unroll
      for (int k = 0; k < 8; ++k) {
        union { unsigned int u; float f; } hv;
        hv.u = ((unsigned int)(unsigned short)h1[k]) << 16;
        acc = fmaf(hv.f, lw[8 + k], acc);
      }
      acc += __shfl_xor(acc, 4);
      acc += __shfl_xor(acc, 2);
      acc += __shfl_xor(acc, 1);
      if (sub == 0) {
        float ns = s_state[o] + acc + lnb[oi];
        s_state[o] = ns;
        out[((size_t)(b * 64 + a0 + a) * T + t) * 2 + oi] = ns;
      }
    }
    __syncthreads();
  }
}

// ---------------------------------------------------------------- launch ----
extern "C" void kernel_launch(void* const* d_in, const int* in_sizes, int n_in,
                              void* d_out, int out_size, void* d_ws, size_t ws_size,
                              hipStream_t stream) {
  (void)in_sizes; (void)n_in; (void)out_size; (void)ws_size;
  const float* cf = (const float*)d_in[0];
  const int* cav = (const int*)d_in[1];
  const float* hid = (const float*)d_in[2];
  const float* ctx = (const float*)d_in[3];
  const float* emb = (const float*)d_in[4];
  const int* mav = (const int*)d_in[5];
  const int* ntp = (const int*)d_in[6];
  const float* w1 = (const float*)d_in[7];
  const float* b1 = (const float*)d_in[8];
  const float* w2 = (const float*)d_in[9];
  const float* b2 = (const float*)d_in[10];
  const float* w3 = (const float*)d_in[11];
  const float* b3 = (const float*)d_in[12];
  const float* wq = (const float*)d_in[13];
  const float* bq = (const float*)d_in[14];
  const float* wk = (const float*)d_in[15];
  const float* bk = (const float*)d_in[16];
  const float* wv = (const float*)d_in[17];
  const float* bv = (const float*)d_in[18];
  const float* wo = (const float*)d_in[19];
  const float* bo = (const float*)d_in[20];
  const float* wih = (const float*)d_in[21];  // w_ih
  const float* whh = (const float*)d_in[22];  // w_hh
  const float* bih = (const float*)d_in[23];  // b_ih
  const float* bhh = (const float*)d_in[24];  // b_hh
  const float* lnw = (const float*)d_in[25];
  const float* lnb = (const float*)d_in[26];

  char* ws = (char*)d_ws;
  unsigned char* K8 = (unsigned char*)(ws + 0);         // 8,388,608
  unsigned char* V8 = (unsigned char*)(ws + 8388608);   // 8,388,608
  unsigned short* WQs = (unsigned short*)(ws + 16777216);
  unsigned short* WOs = (unsigned short*)(ws + 16809984);
  unsigned short* W2s = (unsigned short*)(ws + 16842752);
  unsigned short* W3s = (unsigned short*)(ws + 16859136);
  unsigned short* WIHs = (unsigned short*)(ws + 16875520);
  unsigned short* WHHs = (unsigned short*)(ws + 17006592);
  float* B4s = (float*)(ws + 17137664);
  float* BQSs = (float*)(ws + 17139712);

  (void)hipFuncSetAttribute((const void*)kv_kernel,
                            hipFuncAttributeMaxDynamicSharedMemorySize, 99072);
  (void)hipFuncSetAttribute((const void*)decoder_kernel,
                            hipFuncAttributeMaxDynamicSharedMemorySize, 162560);

  convert_kernel<<<707, 256, 0, stream>>>(wq, wo, w2, w3, wih, whh, bih, bhh, bq,
                                          WQs, WOs, W2s, W3s, WIHs, WHHs, B4s, BQSs);
  kv_kernel<<<1024, 256, 99072, stream>>>(emb, wk, bk, wv, bv, K8, V8);
  decoder_kernel<<<256, 512, 162560, stream>>>(
      cf, cav, hid, ctx, mav, ntp, w1, b1, b2, b3, bo, K8, V8, WQs, WOs, W2s, W3s,
      WIHs, WHHs, B4s, BQSs, lnw, lnb, (float*)d_out);
}

// Round 2
// 1976.130 us; speedup vs baseline: 1.3221x; 1.1914x over previous
//
#include <hip/hip_runtime.h>
#include <cstdint>
#include <cstddef>

// Decoder_55654186222328 — MI355X, R10: weight folding + fewer barriers +
// register-resident LSTM weights + P4 software pipeline.
// R9 post-mortem: R8->R9 delta == conflict-cycle removal exactly; the ~2.1ms
// "base" is a 9-barrier/step latency pipeline at 2 waves/SIMD, plus a
// step-invariant weight stream missing L2 (FETCH 2.36GB/dispatch).
// R10:
//  * e is only used by q  -> fold W3 into WQ  (WQ3 = QSCALE*WQ@W3): phase P2
//    gone, P3's K halves (128->64).
//  * x is only used by the gates -> fold WO into WIH (WIHO = WIH@WO, bias
//    B4p = b_ih+b_hh+WIH@bo): phase P5 gone.
//  * P3->P4 is a pure same-wave dependency (wave nt==h produces exactly the
//    q-columns head h consumes): barrier removed; qf8 lives in bufA (dead
//    after P1), o goes to bufB. Barriers/step: 9 -> 6.
//  * WIHO/WHH/WQ3 fragments cached in persistent VGPRs across all 80 steps
//    (step-invariant; kills the global weight stream + P6 load latency).
//  * P4 chunk loop: explicit next-chunk vA/kB prefetch regs (LDS latency
//    hides under previous chunk's exp/pack/MFMA).
// 256 blocks (128 b x 2 agent halves of 32) x 512 threads, 1 block/CU,
// LDS 162560 B.

typedef short short8 __attribute__((ext_vector_type(8)));
typedef float f32x4 __attribute__((ext_vector_type(4)));

#define LOG2E 1.4426950408889634f
#define QSCALE 0.36067376022224085f /* log2(e)/4 */

__device__ __forceinline__ unsigned short f2bf(float f) {
  union { float f; unsigned int u; } v; v.f = f;
  unsigned int u = v.u;
  return (unsigned short)((u + 0x7fffu + ((u >> 16) & 1u)) >> 16);  // RNE
}
__device__ __forceinline__ float sigm(float x) {
  return 1.f / (1.f + exp2f(-LOG2E * x));
}
__device__ __forceinline__ float tanh_f(float x) {
  return 1.f - 2.f / (1.f + exp2f(2.f * LOG2E * x));
}
__device__ __forceinline__ f32x4 splat4(float v) { f32x4 r = {v, v, v, v}; return r; }
__device__ __forceinline__ unsigned char f2fp8(float x) {
  return (unsigned char)__builtin_amdgcn_cvt_pk_fp8_f32(x, x, 0, false);
}
__device__ __forceinline__ f32x4 mfma_fp8(long a, long b, f32x4 c) {
  return __builtin_amdgcn_mfma_f32_16x16x32_fp8_fp8(a, b, c, 0, 0, 0);
}
__device__ __forceinline__ f32x4 mfma_bf16(short8 a, short8 b, f32x4 c) {
  return __builtin_amdgcn_mfma_f32_16x16x32_bf16(a, b, c, 0, 0, 0);
}

// ---------------------------------------------------------------- convert ----
// W2 (bf16) + WHH (bf16). Folded weights are produced by the fold kernels.
__global__ __launch_bounds__(256) void convert_kernel(
    const float* __restrict__ w2, const float* __restrict__ whh,
    unsigned short* __restrict__ W2, unsigned short* __restrict__ WHH) {
  int i = blockIdx.x * 256 + threadIdx.x;
  if (i >= 73728) return;
  if (i < 8192) W2[i] = f2bf(w2[i]);
  else          WHH[i - 8192] = f2bf(whh[i - 8192]);
}

// ------------------------------------------------------------- fold WIHO ----
// WIHO[r][d] = sum_n wih[r][n] * wo[n][d]   (512x128, K=128), bf16 out.
__global__ __launch_bounds__(256) void fold_wiho_kernel(
    const float* __restrict__ wih, const float* __restrict__ wo,
    unsigned short* __restrict__ WIHO) {
  int i = blockIdx.x * 256 + threadIdx.x;  // 65536
  int r = i >> 7, d = i & 127;
  float acc = 0.f;
  for (int n = 0; n < 128; ++n) acc = fmaf(wih[r * 128 + n], wo[n * 128 + d], acc);
  WIHO[i] = f2bf(acc);
}

// ------------------------------------------------- fold WQ3 + biases --------
// WQ3[n][k] = QSCALE * sum_j wq[n][j]*w3[j][k]   (128x64), bf16.
// B4p[r]    = bih[r] + bhh[r] + sum_n wih[r][n]*bo[n]      (512), f32.
// BQ3S[n]   = QSCALE * (sum_j wq[n][j]*b3[j] + bq[n])      (128), f32.
__global__ __launch_bounds__(256) void fold_wq3b_kernel(
    const float* __restrict__ wq, const float* __restrict__ w3,
    const float* __restrict__ b3, const float* __restrict__ bq,
    const float* __restrict__ wih, const float* __restrict__ bo,
    const float* __restrict__ bih, const float* __restrict__ bhh,
    unsigned short* __restrict__ WQ3, float* __restrict__ B4p,
    float* __restrict__ BQ3S) {
  int i = blockIdx.x * 256 + threadIdx.x;
  if (i < 8192) {
    int n = i >> 6, k = i & 63;
    float acc = 0.f;
    for (int j = 0; j < 128; ++j) acc = fmaf(wq[n * 128 + j], w3[j * 64 + k], acc);
    WQ3[i] = f2bf(acc * QSCALE);
  } else if (i < 8704) {
    int r = i - 8192;
    float acc = bih[r] + bhh[r];
    for (int n = 0; n < 128; ++n) acc = fmaf(wih[r * 128 + n], bo[n], acc);
    B4p[r] = acc;
  } else if (i < 8832) {
    int n = i - 8704;
    float acc = bq[n];
    for (int j = 0; j < 128; ++j) acc = fmaf(wq[n * 128 + j], b3[j], acc);
    BQ3S[n] = acc * QSCALE;
  }
}

// ---------------------------------------------------------------- K/V --------
// K8[b][m][128] fp8; V8[b][d][512] fp8 (transposed, m-permuted within each
// 32-token chunk: byte slot s holds token pi(s), pi(8q+j)=4q+j (j<4) else
// 16+4q+(j-4), matching the decoder's in-register P fragment ordering).
// grid 1024 = 128 b x 8 chunks.
__global__ __launch_bounds__(256) void kv_kernel(
    const float* __restrict__ emb, const float* __restrict__ wk,
    const float* __restrict__ bk, const float* __restrict__ wv,
    const float* __restrict__ bv,
    unsigned char* __restrict__ K8, unsigned char* __restrict__ V8) {
  extern __shared__ char smem[];
  float* s_e = (float*)smem;            // [64][129]
  float* s_w = (float*)(smem + 33024);  // [128][129]
  const int tid = threadIdx.x;
  const int b = blockIdx.x >> 3;
  const int m0 = (blockIdx.x & 7) * 64;

  for (int i = tid; i < 8192; i += 256) {
    int row = i >> 7, col = i & 127;
    s_e[row * 129 + col] = emb[(size_t)(b * 512 + m0 + row) * 128 + col];
  }
  for (int i = tid; i < 16384; i += 256) {
    int row = i >> 7, col = i & 127;
    s_w[row * 129 + col] = wk[i];
  }
  __syncthreads();
  {  // K rows -> fp8
    const int dg = tid & 31, rg = tid >> 5;
    float acc[8][4];
#pragma unroll
    for (int rr = 0; rr < 8; ++rr)
#pragma unroll
      for (int j = 0; j < 4; ++j) acc[rr][j] = 0.f;
    for (int k = 0; k < 128; ++k) {
      float e[8];
#pragma unroll
      for (int rr = 0; rr < 8; ++rr) e[rr] = s_e[(rg * 8 + rr) * 129 + k];
#pragma unroll
      for (int j = 0; j < 4; ++j) {
        float w = s_w[(dg * 4 + j) * 129 + k];
#pragma unroll
        for (int rr = 0; rr < 8; ++rr) acc[rr][j] = fmaf(e[rr], w, acc[rr][j]);
      }
    }
#pragma unroll
    for (int rr = 0; rr < 8; ++rr)
#pragma unroll
      for (int j = 0; j < 4; ++j) {
        int d = dg * 4 + j;
        K8[(size_t)(b * 512 + m0 + rg * 8 + rr) * 128 + d] = f2fp8(acc[rr][j] + bk[d]);
      }
  }
  __syncthreads();
  for (int i = tid; i < 16384; i += 256) {
    int row = i >> 7, col = i & 127;
    s_w[row * 129 + col] = wv[i];
  }
  __syncthreads();
  {  // V transposed + m-permuted -> fp8
    const int r = tid & 63, dg = tid >> 6;
    float acc[32];
#pragma unroll
    for (int j = 0; j < 32; ++j) acc[j] = 0.f;
    for (int k = 0; k < 128; ++k) {
      float e = s_e[r * 129 + k];
#pragma unroll
      for (int j = 0; j < 32; ++j) acc[j] = fmaf(e, s_w[(dg * 32 + j) * 129 + k], acc[j]);
    }
    const int m = m0 + r;
    const int ml = m & 31;
    const int sperm = (ml < 16) ? (((ml >> 2) << 3) | (ml & 3))
                                : ((((ml - 16) >> 2) << 3) | ((ml - 16) & 3) | 4);
    const int mpos = (m & ~31) | sperm;
#pragma unroll
    for (int j = 0; j < 32; ++j) {
      int d = dg * 32 + j;
      V8[(size_t)(b * 128 + d) * 512 + mpos] = f2fp8(acc[j] + bv[d]);
    }
  }
}

// ---------------------------------------------------------------- decoder ----
// grid 256 = 128 b x 2 agent-halves (32 agents). 512 threads = 8 waves.
// LDS (162560 B, 1 block/CU):
//   sK    @0      fp8 [512][128] XOR-swz  65536   (persistent)
//   sV    @65536  fp8 [128][512] XOR-swz  65536   (persistent, transposed+pi)
//   bufA  @131072 u16 [32][136]            8704   (h1 | qf8 bytes [32][136])
//   bufB  @139776 u16 [32][136]            8704   (o)
//   s_h   @148480 u16 [32][136]            8704
//   zone  @157184 h2 u16 [32][72]          4608
//   state @161792 f32 [64]                  256
//   maskb @162048 u8 [512]                  512
// Per-step phases/barriers (6): P0|P1|P3+P4|P6a|P6b|P7.
__global__ __launch_bounds__(512, 2) void decoder_kernel(
    const float* __restrict__ cf, const int* __restrict__ cav,
    const float* __restrict__ hid,
    const float* __restrict__ ctx, const int* __restrict__ mav,
    const int* __restrict__ ntp,
    const float* __restrict__ w1, const float* __restrict__ b1,
    const float* __restrict__ b2,
    const unsigned char* __restrict__ K8, const unsigned char* __restrict__ V8,
    const unsigned short* __restrict__ W2, const unsigned short* __restrict__ WQ3,
    const unsigned short* __restrict__ WIHO, const unsigned short* __restrict__ WHH,
    const float* __restrict__ B4p, const float* __restrict__ BQ3S,
    const float* __restrict__ lnw, const float* __restrict__ lnb,
    float* __restrict__ out) {
  extern __shared__ char smem[];
  unsigned short* s_bufA = (unsigned short*)(smem + 131072);
  unsigned short* s_bufB = (unsigned short*)(smem + 139776);
  unsigned short* s_h = (unsigned short*)(smem + 148480);
  unsigned short* s_h2 = (unsigned short*)(smem + 157184);
  float* s_state = (float*)(smem + 161792);
  unsigned char* s_maskb = (unsigned char*)(smem + 162048);

  const int tid = threadIdx.x;
  const int wave = tid >> 6;
  const int lane = tid & 63;
  const int quad = lane >> 4;
  const int l16 = lane & 15;

  const int b = blockIdx.x & 127;
  const int a0 = (blockIdx.x >> 7) * 32;
  const int T = *ntp;
  const f32x4 zero4 = {0.f, 0.f, 0.f, 0.f};
  const long kOnes = 0x3838383838383838L;  // fp8 e4m3 1.0 x8

  // ---- preload persistent K/V into LDS with XOR swizzle ----
  {
    const unsigned long long* Kg = (const unsigned long long*)(K8 + (size_t)b * 65536);
    for (int i = tid; i < 8192; i += 512) {
      int tok = i >> 4, seg = i & 15;
      *(unsigned long long*)(smem + tok * 128 + ((seg * 8) ^ ((tok & 15) * 8))) =
          Kg[(size_t)tok * 16 + seg];
    }
    const unsigned long long* Vg = (const unsigned long long*)(V8 + (size_t)b * 65536);
    for (int i = tid; i < 8192; i += 512) {
      int d = i >> 6, seg = i & 63;
      *(unsigned long long*)(smem + 65536 + d * 512 + ((seg * 8) ^ ((d & 15) * 8))) =
          Vg[(size_t)d * 64 + seg];
    }
  }
  // ---- init ----
  if (tid < 64) {
    int a = tid >> 1, oi = tid & 1;
    s_state[a * 2 + oi] = cf[(size_t)(b * 64 + a0 + a) * 2 + oi];
  }
  s_maskb[tid] = mav[b * 512 + tid] ? 1 : 0;
  {  // h0 (32 agents x 128 -> 8 per thread)
    int idx = tid * 8;
    int a = idx >> 7, n0 = idx & 127;
    const float* hp = hid + (size_t)(b * 64 + a0 + a) * 128 + n0;
    short8 v;
#pragma unroll
    for (int j = 0; j < 8; ++j) v[j] = (short)f2bf(hp[j]);
    *(short8*)(s_h + a * 136 + n0) = v;
  }
  float c_reg[2][4], avl[2][4];
#pragma unroll
  for (int mt = 0; mt < 2; ++mt)
#pragma unroll
    for (int r = 0; r < 4; ++r) {
      int a = mt * 16 + quad * 4 + r;
      c_reg[mt][r] = ctx[(size_t)(b * 64 + a0 + a) * 128 + wave * 16 + l16];
      avl[mt][r] = (cav[b * 64 + a0 + a] != 0) ? 1.f : 0.f;
    }

  // ---- persistent register-cached weights (step-invariant) ----
  const int wrow = wave * 16 + l16;
  short8 rIH[4][4], rHH[4][4];
#pragma unroll
  for (int kt = 0; kt < 4; ++kt)
#pragma unroll
    for (int g = 0; g < 4; ++g) {
      rIH[kt][g] = *(const short8*)(WIHO + ((g * 128 + wrow) * 128 + kt * 32 + quad * 8));
      rHH[kt][g] = *(const short8*)(WHH + ((g * 128 + wrow) * 128 + kt * 32 + quad * 8));
    }
  short8 rWQ3[2];
#pragma unroll
  for (int kt = 0; kt < 2; ++kt)
    rWQ3[kt] = *(const short8*)(WQ3 + (wrow * 64 + kt * 32 + quad * 8));
  float rB4[4];
#pragma unroll
  for (int g = 0; g < 4; ++g) rB4[g] = B4p[g * 128 + wrow];
  const float rBQ3 = BQ3S[wrow];
  const float rB2 = b2[(wave & 3) * 16 + l16];
  __syncthreads();

  // per-lane mask flags: bit i set when token i*16+l16 is NOT available.
  unsigned mflags = 0;
#pragma unroll
  for (int i = 0; i < 32; ++i)
    if (!s_maskb[i * 16 + l16]) mflags |= (1u << i);

#pragma unroll 1
  for (int t = 0; t < T; ++t) {
    // ---- P0: h1 = relu(state @ w1^T + b1) -> bufA ----
    {
      int a = tid >> 4, n0 = (tid & 15) * 8;
      float st0 = s_state[a * 2], st1 = s_state[a * 2 + 1];
      const float* wp = w1 + n0 * 2;
      const float* bp = b1 + n0;
      short8 v;
#pragma unroll
      for (int j = 0; j < 8; ++j) {
        float x = fmaf(wp[j * 2], st0, fmaf(wp[j * 2 + 1], st1, bp[j]));
        v[j] = (short)f2bf(fmaxf(x, 0.f));
      }
      *(short8*)(s_bufA + a * 136 + n0) = v;
    }
    __syncthreads();

    // ---- P1: h2 = relu(h1 @ w2^T + b2)  M32 N64 K128 -> zone ----
    {
      int mt = wave >> 2, nt = wave & 3;
      f32x4 acc = splat4(rB2);
#pragma unroll
      for (int kt = 0; kt < 4; ++kt) {
        short8 a8 = *(const short8*)(s_bufA + (mt * 16 + l16) * 136 + kt * 32 + quad * 8);
        short8 b8 = *(const short8*)(W2 + ((nt * 16 + l16) * 128 + kt * 32 + quad * 8));
        acc = mfma_bf16(a8, b8, acc);
      }
#pragma unroll
      for (int r = 0; r < 4; ++r)
        s_h2[(mt * 16 + quad * 4 + r) * 72 + nt * 16 + l16] = f2bf(fmaxf(acc[r], 0.f));
    }
    __syncthreads();

    // ---- P3: q = h2 @ WQ3^T + bq3 -> fp8 in bufA bytes (h1 dead) ----
    // wave nt==h produces exactly head h's q-columns -> no barrier before P4.
    unsigned char* s_q8 = (unsigned char*)s_bufA;
    {
#pragma unroll
      for (int mt = 0; mt < 2; ++mt) {
        f32x4 acc = splat4(rBQ3);
#pragma unroll
        for (int kt = 0; kt < 2; ++kt) {
          short8 a8 = *(const short8*)(s_h2 + (mt * 16 + l16) * 72 + kt * 32 + quad * 8);
          acc = mfma_bf16(a8, rWQ3[kt], acc);
        }
#pragma unroll
        for (int r = 0; r < 4; ++r)
          s_q8[(mt * 16 + quad * 4 + r) * 136 + wave * 16 + l16] = f2fp8(acc[r]);
      }
    }
    __asm__ volatile("s_waitcnt lgkmcnt(0)" ::: "memory");
    __builtin_amdgcn_sched_barrier(0);

    // ---- P4: attention — swapped-operand MFMA, P in registers, prefetched ----
    {
      const int h = wave;
      const char* sKb = (const char*)smem;
      const char* sVrow = (const char*)(smem + 65536) + (h * 16 + l16) * 512;
      long qA[2];
#pragma unroll
      for (int mt = 0; mt < 2; ++mt)
        qA[mt] = (quad < 2)
                     ? *(const long*)(s_q8 + (mt * 16 + l16) * 136 + h * 16 + quad * 8)
                     : (quad == 2 ? 0xF8L : 0L);  // byte0 = fp8 -256
      const int koff = (h * 16 + quad * 8) ^ (l16 * 8);
      f32x4 O[2], L4[2];
      O[0] = zero4; O[1] = zero4; L4[0] = zero4; L4[1] = zero4;
      // prefetch chunk 0
      long vA_c = *(const long*)(sVrow + ((quad * 8) ^ (l16 * 8)));
      long kB_c0 = 0L, kB_c1 = 0L;
      if (quad < 2) {
        kB_c0 = *(const long*)(sKb + (size_t)l16 * 128 + koff);
        kB_c1 = *(const long*)(sKb + (size_t)(16 + l16) * 128 + koff);
      }
#pragma unroll 2
      for (int c = 0; c < 16; ++c) {
        long vA_n = 0L, kB_n0 = 0L, kB_n1 = 0L;
        if (c < 15) {
          vA_n = *(const long*)(sVrow + (((c + 1) * 32 + quad * 8) ^ (l16 * 8)));
          if (quad < 2) {
            kB_n0 = *(const long*)(sKb + (size_t)((c + 1) * 32 + l16) * 128 + koff);
            kB_n1 = *(const long*)(sKb + (size_t)((c + 1) * 32 + 16 + l16) * 128 + koff);
          }
        }
        long kB0 = kB_c0, kB1 = kB_c1;
        if (quad == 2) {
          kB0 = ((mflags >> (c * 2)) & 1u) ? 0x38L : 0L;      // fp8 1.0 flag
          kB1 = ((mflags >> (c * 2 + 1)) & 1u) ? 0x38L : 0L;
        }
        f32x4 S2[2][2];
        S2[0][0] = mfma_fp8(kB0, qA[0], zero4);
        S2[0][1] = mfma_fp8(kB0, qA[1], zero4);
        S2[1][0] = mfma_fp8(kB1, qA[0], zero4);
        S2[1][1] = mfma_fp8(kB1, qA[1], zero4);
#pragma unroll
        for (int mt = 0; mt < 2; ++mt) {
          unsigned w0 = (unsigned)__builtin_amdgcn_cvt_pk_fp8_f32(
              exp2f(S2[0][mt][0]), exp2f(S2[0][mt][1]), 0, false);
          w0 = (unsigned)__builtin_amdgcn_cvt_pk_fp8_f32(
              exp2f(S2[0][mt][2]), exp2f(S2[0][mt][3]), (int)w0, true);
          unsigned w1v = (unsigned)__builtin_amdgcn_cvt_pk_fp8_f32(
              exp2f(S2[1][mt][0]), exp2f(S2[1][mt][1]), 0, false);
          w1v = (unsigned)__builtin_amdgcn_cvt_pk_fp8_f32(
              exp2f(S2[1][mt][2]), exp2f(S2[1][mt][3]), (int)w1v, true);
          long pB = (long)(((unsigned long long)w1v << 32) | (unsigned long long)w0);
          O[mt] = mfma_fp8(vA_c, pB, O[mt]);     // O^T: rows d-local, cols a
          L4[mt] = mfma_fp8(kOnes, pB, L4[mt]);
        }
        vA_c = vA_n; kB_c0 = kB_n0; kB_c1 = kB_n1;
      }
      // o -> bufB; O^T lane layout: d = h*16+quad*4+r, a = mt*16+l16
#pragma unroll
      for (int mt = 0; mt < 2; ++mt) {
        unsigned long long ow = 0;
#pragma unroll
        for (int r = 0; r < 4; ++r)
          ow |= (unsigned long long)f2bf(O[mt][r] / L4[mt][r]) << (16 * r);
        *(unsigned long long*)(s_bufB + (mt * 16 + l16) * 136 + h * 16 + quad * 4) = ow;
      }
    }
    __syncthreads();

    // ---- P6a: LSTM gates (x-part folded through WO; weights in regs) ----
    {
      const int ni = wave;
      f32x4 gi[2], gf[2], gg[2], go[2];
#pragma unroll
      for (int mt = 0; mt < 2; ++mt) {
        gi[mt] = splat4(rB4[0]);
        gf[mt] = splat4(rB4[1]);
        gg[mt] = splat4(rB4[2]);
        go[mt] = splat4(rB4[3]);
      }
#pragma unroll
      for (int kt = 0; kt < 4; ++kt)
#pragma unroll
        for (int mt = 0; mt < 2; ++mt) {
          short8 a8 = *(const short8*)(s_bufB + (mt * 16 + l16) * 136 + kt * 32 + quad * 8);
          gi[mt] = mfma_bf16(a8, rIH[kt][0], gi[mt]);
          gf[mt] = mfma_bf16(a8, rIH[kt][1], gf[mt]);
          gg[mt] = mfma_bf16(a8, rIH[kt][2], gg[mt]);
          go[mt] = mfma_bf16(a8, rIH[kt][3], go[mt]);
        }
#pragma unroll
      for (int kt = 0; kt < 4; ++kt)
#pragma unroll
        for (int mt = 0; mt < 2; ++mt) {
          short8 a8 = *(const short8*)(s_h + (mt * 16 + l16) * 136 + kt * 32 + quad * 8);
          gi[mt] = mfma_bf16(a8, rHH[kt][0], gi[mt]);
          gf[mt] = mfma_bf16(a8, rHH[kt][1], gf[mt]);
          gg[mt] = mfma_bf16(a8, rHH[kt][2], gg[mt]);
          go[mt] = mfma_bf16(a8, rHH[kt][3], go[mt]);
        }
      float hnew[2][4];
#pragma unroll
      for (int mt = 0; mt < 2; ++mt)
#pragma unroll
        for (int r = 0; r < 4; ++r) {
          float iv = sigm(gi[mt][r]);
          float fv = sigm(gf[mt][r]);
          float gv = tanh_f(gg[mt][r]);
          float ov = sigm(go[mt][r]);
          float cn = fmaf(fv, c_reg[mt][r], iv * gv);
          float hv = ov * tanh_f(cn);
          int arow = mt * 16 + quad * 4 + r;
          float av = avl[mt][r];
          union { unsigned int u; float f; } ho;
          ho.u = ((unsigned int)s_h[arow * 136 + ni * 16 + l16]) << 16;
          c_reg[mt][r] = av * cn + (1.f - av) * c_reg[mt][r];
          hnew[mt][r] = av * hv + (1.f - av) * ho.f;
        }
      __syncthreads();  // all h reads (incl. MFMA A-frags) done before overwrite
#pragma unroll
      for (int mt = 0; mt < 2; ++mt)
#pragma unroll
        for (int r = 0; r < 4; ++r) {
          int arow = mt * 16 + quad * 4 + r;
          s_h[arow * 136 + ni * 16 + l16] = f2bf(hnew[mt][r]);
        }
    }
    __syncthreads();

    // ---- P7: state += h @ lin_w^T + lin_b; emit (all 512 threads) ----
    {
      int o = tid >> 3;        // 0..63 = a*2+oi
      int sub = tid & 7;       // 8 threads per output, 16 k each
      int a = o >> 1, oi = o & 1;
      const unsigned short* hp = s_h + a * 136 + sub * 16;
      const float* lw = lnw + oi * 128 + sub * 16;
      short8 h0 = *(const short8*)hp;
      short8 h1 = *(const short8*)(hp + 8);
      float acc = 0.f;
#pragma unroll
      for (int k = 0; k < 8; ++k) {
        union { unsigned int u; float f; } hv;
        hv.u = ((unsigned int)(unsigned short)h0[k]) << 16;
        acc = fmaf(hv.f, lw[k], acc);
      }
#pragma unroll
      for (int k = 0; k < 8; ++k) {
        union { unsigned int u; float f; } hv;
        hv.u = ((unsigned int)(unsigned short)h1[k]) << 16;
        acc = fmaf(hv.f, lw[8 + k], acc);
      }
      acc += __shfl_xor(acc, 4);
      acc += __shfl_xor(acc, 2);
      acc += __shfl_xor(acc, 1);
      if (sub == 0) {
        float ns = s_state[o] + acc + lnb[oi];
        s_state[o] = ns;
        out[((size_t)(b * 64 + a0 + a) * T + t) * 2 + oi] = ns;
      }
    }
    __syncthreads();
  }
}

// ---------------------------------------------------------------- launch ----
extern "C" void kernel_launch(void* const* d_in, const int* in_sizes, int n_in,
                              void* d_out, int out_size, void* d_ws, size_t ws_size,
                              hipStream_t stream) {
  (void)in_sizes; (void)n_in; (void)out_size; (void)ws_size;
  const float* cf = (const float*)d_in[0];
  const int* cav = (const int*)d_in[1];
  const float* hid = (const float*)d_in[2];
  const float* ctx = (const float*)d_in[3];
  const float* emb = (const float*)d_in[4];
  const int* mav = (const int*)d_in[5];
  const int* ntp = (const int*)d_in[6];
  const float* w1 = (const float*)d_in[7];
  const float* b1 = (const float*)d_in[8];
  const float* w2 = (const float*)d_in[9];
  const float* b2 = (const float*)d_in[10];
  const float* w3 = (const float*)d_in[11];
  const float* b3 = (const float*)d_in[12];
  const float* wq = (const float*)d_in[13];
  const float* bq = (const float*)d_in[14];
  const float* wk = (const float*)d_in[15];
  const float* bk = (const float*)d_in[16];
  const float* wv = (const float*)d_in[17];
  const float* bv = (const float*)d_in[18];
  const float* wo = (const float*)d_in[19];
  const float* bo = (const float*)d_in[20];
  const float* wih = (const float*)d_in[21];  // w_ih
  const float* whh = (const float*)d_in[22];  // w_hh
  const float* bih = (const float*)d_in[23];  // b_ih
  const float* bhh = (const float*)d_in[24];  // b_hh
  const float* lnw = (const float*)d_in[25];
  const float* lnb = (const float*)d_in[26];

  char* ws = (char*)d_ws;
  unsigned char* K8 = (unsigned char*)(ws + 0);         // 8,388,608
  unsigned char* V8 = (unsigned char*)(ws + 8388608);   // 8,388,608
  unsigned short* W2s = (unsigned short*)(ws + 16777216);   // 16,384 B
  unsigned short* WQ3s = (unsigned short*)(ws + 16793600);  // 16,384 B
  unsigned short* WIHOs = (unsigned short*)(ws + 16809984); // 131,072 B
  unsigned short* WHHs = (unsigned short*)(ws + 16941056);  // 131,072 B
  float* B4p = (float*)(ws + 17072128);                     // 2,048 B
  float* BQ3S = (float*)(ws + 17074176);                    // 512 B

  (void)hipFuncSetAttribute((const void*)kv_kernel,
                            hipFuncAttributeMaxDynamicSharedMemorySize, 99072);
  (void)hipFuncSetAttribute((const void*)decoder_kernel,
                            hipFuncAttributeMaxDynamicSharedMemorySize, 162560);

  convert_kernel<<<288, 256, 0, stream>>>(w2, whh, W2s, WHHs);
  fold_wiho_kernel<<<256, 256, 0, stream>>>(wih, wo, WIHOs);
  fold_wq3b_kernel<<<35, 256, 0, stream>>>(wq, w3, b3, bq, wih, bo, bih, bhh,
                                           WQ3s, B4p, BQ3S);
  kv_kernel<<<1024, 256, 99072, stream>>>(emb, wk, bk, wv, bv, K8, V8);
  decoder_kernel<<<256, 512, 162560, stream>>>(
      cf, cav, hid, ctx, mav, ntp, w1, b1, b2, K8, V8, W2s, WQ3s, WIHOs, WHHs,
      B4p, BQ3S, lnw, lnb, (float*)d_out);
}

// Round 5
// 1293.017 us; speedup vs baseline: 2.0205x; 1.5283x over previous
//
#include <hip/hip_runtime.h>
#include <cstdint>
#include <cstddef>

// Decoder_55654186222328 — MI355X, R13: R12 with trans-op BUILTINS (hazard fix).
// R11/R12 post-mortem (FAILED 0.235 / 1.899): raw inline-asm v_exp_f32 /
// v_rcp_f32 violate CDNA's trans-op waitstate rule — a consumer of a trans
// op's dest VGPR needs a manually-inserted wait state; the compiler's hazard
// recognizer can't see inside an asm blob, so no s_nop was emitted and
// consumers read stale registers. Error magnitude changing between R11/R12
// (scheduling reshuffle) is the fingerprint. Fix: __builtin_amdgcn_exp2f /
// __builtin_amdgcn_rcpf (same instructions, compiler-managed hazards).
// Kept from R12: software-RNE f2bf everywhere (cvt_pk rounding left un-risked),
// fused P7+P0 register state (5 barriers/step), register-cached LSTM/WQ3
// weights, P4 swapped-operand in-register-P attention with prefetch.
// 256 blocks (128 b x 2 agent halves of 32) x 512 threads, 1 block/CU,
// LDS 162560 B.

typedef short short8 __attribute__((ext_vector_type(8)));
typedef float f32x4 __attribute__((ext_vector_type(4)));

#define LOG2E 1.4426950408889634f
#define QSCALE 0.36067376022224085f /* log2(e)/4 */

__device__ __forceinline__ unsigned short f2bf(float f) {
  union { float f; unsigned int u; } v; v.f = f;
  unsigned int u = v.u;
  return (unsigned short)((u + 0x7fffu + ((u >> 16) & 1u)) >> 16);  // RNE
}
__device__ __forceinline__ float fexp2(float x) {
  return __builtin_amdgcn_exp2f(x);   // v_exp_f32 with proper hazard handling
}
__device__ __forceinline__ float frcp(float x) {
  return __builtin_amdgcn_rcpf(x);    // v_rcp_f32 with proper hazard handling
}
__device__ __forceinline__ float sigm(float x) {
  return frcp(1.f + fexp2(-LOG2E * x));
}
__device__ __forceinline__ float tanh_f(float x) {
  return 1.f - 2.f * frcp(1.f + fexp2(2.f * LOG2E * x));
}
__device__ __forceinline__ f32x4 splat4(float v) { f32x4 r = {v, v, v, v}; return r; }
__device__ __forceinline__ unsigned char f2fp8(float x) {
  return (unsigned char)__builtin_amdgcn_cvt_pk_fp8_f32(x, x, 0, false);
}
__device__ __forceinline__ f32x4 mfma_fp8(long a, long b, f32x4 c) {
  return __builtin_amdgcn_mfma_f32_16x16x32_fp8_fp8(a, b, c, 0, 0, 0);
}
__device__ __forceinline__ f32x4 mfma_bf16(short8 a, short8 b, f32x4 c) {
  return __builtin_amdgcn_mfma_f32_16x16x32_bf16(a, b, c, 0, 0, 0);
}

// ---------------------------------------------------------------- convert ----
__global__ __launch_bounds__(256) void convert_kernel(
    const float* __restrict__ w2, const float* __restrict__ whh,
    unsigned short* __restrict__ W2, unsigned short* __restrict__ WHH) {
  int i = blockIdx.x * 256 + threadIdx.x;
  if (i >= 73728) return;
  if (i < 8192) W2[i] = f2bf(w2[i]);
  else          WHH[i - 8192] = f2bf(whh[i - 8192]);
}

// ------------------------------------------------------------- fold WIHO ----
// WIHO[r][d] = sum_n wih[r][n] * wo[n][d]   (512x128, K=128), bf16 out.
__global__ __launch_bounds__(256) void fold_wiho_kernel(
    const float* __restrict__ wih, const float* __restrict__ wo,
    unsigned short* __restrict__ WIHO) {
  int i = blockIdx.x * 256 + threadIdx.x;  // 65536
  int r = i >> 7, d = i & 127;
  float acc = 0.f;
  for (int n = 0; n < 128; ++n) acc = fmaf(wih[r * 128 + n], wo[n * 128 + d], acc);
  WIHO[i] = f2bf(acc);
}

// ------------------------------------------------- fold WQ3 + biases --------
__global__ __launch_bounds__(256) void fold_wq3b_kernel(
    const float* __restrict__ wq, const float* __restrict__ w3,
    const float* __restrict__ b3, const float* __restrict__ bq,
    const float* __restrict__ wih, const float* __restrict__ bo,
    const float* __restrict__ bih, const float* __restrict__ bhh,
    unsigned short* __restrict__ WQ3, float* __restrict__ B4p,
    float* __restrict__ BQ3S) {
  int i = blockIdx.x * 256 + threadIdx.x;
  if (i < 8192) {
    int n = i >> 6, k = i & 63;
    float acc = 0.f;
    for (int j = 0; j < 128; ++j) acc = fmaf(wq[n * 128 + j], w3[j * 64 + k], acc);
    WQ3[i] = f2bf(acc * QSCALE);
  } else if (i < 8704) {
    int r = i - 8192;
    float acc = bih[r] + bhh[r];
    for (int n = 0; n < 128; ++n) acc = fmaf(wih[r * 128 + n], bo[n], acc);
    B4p[r] = acc;
  } else if (i < 8832) {
    int n = i - 8704;
    float acc = bq[n];
    for (int j = 0; j < 128; ++j) acc = fmaf(wq[n * 128 + j], b3[j], acc);
    BQ3S[n] = acc * QSCALE;
  }
}

// ---------------------------------------------------------------- K/V --------
// K8[b][m][128] fp8; V8[b][d][512] fp8 (transposed, m-permuted within each
// 32-token chunk: slot s holds token pi(s), pi(8q+j)=4q+j (j<4) else
// 16+4q+(j-4)). grid 1024 = 128 b x 8 chunks.
__global__ __launch_bounds__(256) void kv_kernel(
    const float* __restrict__ emb, const float* __restrict__ wk,
    const float* __restrict__ bk, const float* __restrict__ wv,
    const float* __restrict__ bv,
    unsigned char* __restrict__ K8, unsigned char* __restrict__ V8) {
  extern __shared__ char smem[];
  float* s_e = (float*)smem;            // [64][129]
  float* s_w = (float*)(smem + 33024);  // [128][129]
  const int tid = threadIdx.x;
  const int b = blockIdx.x >> 3;
  const int m0 = (blockIdx.x & 7) * 64;

  for (int i = tid; i < 8192; i += 256) {
    int row = i >> 7, col = i & 127;
    s_e[row * 129 + col] = emb[(size_t)(b * 512 + m0 + row) * 128 + col];
  }
  for (int i = tid; i < 16384; i += 256) {
    int row = i >> 7, col = i & 127;
    s_w[row * 129 + col] = wk[i];
  }
  __syncthreads();
  {  // K rows -> fp8
    const int dg = tid & 31, rg = tid >> 5;
    float acc[8][4];
#pragma unroll
    for (int rr = 0; rr < 8; ++rr)
#pragma unroll
      for (int j = 0; j < 4; ++j) acc[rr][j] = 0.f;
    for (int k = 0; k < 128; ++k) {
      float e[8];
#pragma unroll
      for (int rr = 0; rr < 8; ++rr) e[rr] = s_e[(rg * 8 + rr) * 129 + k];
#pragma unroll
      for (int j = 0; j < 4; ++j) {
        float w = s_w[(dg * 4 + j) * 129 + k];
#pragma unroll
        for (int rr = 0; rr < 8; ++rr) acc[rr][j] = fmaf(e[rr], w, acc[rr][j]);
      }
    }
#pragma unroll
    for (int rr = 0; rr < 8; ++rr)
#pragma unroll
      for (int j = 0; j < 4; ++j) {
        int d = dg * 4 + j;
        K8[(size_t)(b * 512 + m0 + rg * 8 + rr) * 128 + d] = f2fp8(acc[rr][j] + bk[d]);
      }
  }
  __syncthreads();
  for (int i = tid; i < 16384; i += 256) {
    int row = i >> 7, col = i & 127;
    s_w[row * 129 + col] = wv[i];
  }
  __syncthreads();
  {  // V transposed + m-permuted -> fp8
    const int r = tid & 63, dg = tid >> 6;
    float acc[32];
#pragma unroll
    for (int j = 0; j < 32; ++j) acc[j] = 0.f;
    for (int k = 0; k < 128; ++k) {
      float e = s_e[r * 129 + k];
#pragma unroll
      for (int j = 0; j < 32; ++j) acc[j] = fmaf(e, s_w[(dg * 32 + j) * 129 + k], acc[j]);
    }
    const int m = m0 + r;
    const int ml = m & 31;
    const int sperm = (ml < 16) ? (((ml >> 2) << 3) | (ml & 3))
                                : ((((ml - 16) >> 2) << 3) | ((ml - 16) & 3) | 4);
    const int mpos = (m & ~31) | sperm;
#pragma unroll
    for (int j = 0; j < 32; ++j) {
      int d = dg * 32 + j;
      V8[(size_t)(b * 128 + d) * 512 + mpos] = f2fp8(acc[j] + bv[d]);
    }
  }
}

// ---------------------------------------------------------------- decoder ----
// grid 256 = 128 b x 2 agent-halves (32 agents). 512 threads = 8 waves.
// LDS (162560 B, 1 block/CU):
//   sK    @0      fp8 [512][128] XOR-swz  65536   (persistent)
//   sV    @65536  fp8 [128][512] XOR-swz  65536   (persistent, transposed+pi)
//   bufA  @131072 u16 [32][136]            8704   (h1 | qf8 bytes [32][136])
//   bufB  @139776 u16 [32][136]            8704   (o)
//   s_h   @148480 u16 [32][136]            8704
//   zone  @157184 h2 u16 [32][72]          4608
//   maskb @162048 u8 [512]                  512
// Per-step barriers (5): P1|P3+P4|P6c|P6w|P7+P0.
__global__ __launch_bounds__(512, 2) void decoder_kernel(
    const float* __restrict__ cf, const int* __restrict__ cav,
    const float* __restrict__ hid,
    const float* __restrict__ ctx, const int* __restrict__ mav,
    const int* __restrict__ ntp,
    const float* __restrict__ w1, const float* __restrict__ b1,
    const float* __restrict__ b2,
    const unsigned char* __restrict__ K8, const unsigned char* __restrict__ V8,
    const unsigned short* __restrict__ W2, const unsigned short* __restrict__ WQ3,
    const unsigned short* __restrict__ WIHO, const unsigned short* __restrict__ WHH,
    const float* __restrict__ B4p, const float* __restrict__ BQ3S,
    const float* __restrict__ lnw, const float* __restrict__ lnb,
    float* __restrict__ out) {
  extern __shared__ char smem[];
  unsigned short* s_bufA = (unsigned short*)(smem + 131072);
  unsigned short* s_bufB = (unsigned short*)(smem + 139776);
  unsigned short* s_h = (unsigned short*)(smem + 148480);
  unsigned short* s_h2 = (unsigned short*)(smem + 157184);
  unsigned char* s_maskb = (unsigned char*)(smem + 162048);

  const int tid = threadIdx.x;
  const int wave = tid >> 6;
  const int lane = tid & 63;
  const int quad = lane >> 4;
  const int l16 = lane & 15;

  const int b = blockIdx.x & 127;
  const int a0 = (blockIdx.x >> 7) * 32;
  const int T = *ntp;
  const f32x4 zero4 = {0.f, 0.f, 0.f, 0.f};
  const long kOnes = 0x3838383838383838L;  // fp8 e4m3 1.0 x8

  // ---- preload persistent K/V into LDS with XOR swizzle ----
  {
    const unsigned long long* Kg = (const unsigned long long*)(K8 + (size_t)b * 65536);
    for (int i = tid; i < 8192; i += 512) {
      int tok = i >> 4, seg = i & 15;
      *(unsigned long long*)(smem + tok * 128 + ((seg * 8) ^ ((tok & 15) * 8))) =
          Kg[(size_t)tok * 16 + seg];
    }
    const unsigned long long* Vg = (const unsigned long long*)(V8 + (size_t)b * 65536);
    for (int i = tid; i < 8192; i += 512) {
      int d = i >> 6, seg = i & 63;
      *(unsigned long long*)(smem + 65536 + d * 512 + ((seg * 8) ^ ((d & 15) * 8))) =
          Vg[(size_t)d * 64 + seg];
    }
  }
  // ---- init ----
  s_maskb[tid] = mav[b * 512 + tid] ? 1 : 0;
  {  // h0 (32 agents x 128 -> 8 per thread)
    int idx = tid * 8;
    int a = idx >> 7, n0 = idx & 127;
    const float* hp = hid + (size_t)(b * 64 + a0 + a) * 128 + n0;
    short8 v;
#pragma unroll
    for (int j = 0; j < 8; ++j) v[j] = (short)f2bf(hp[j]);
    *(short8*)(s_h + a * 136 + n0) = v;
  }
  float c_reg[2][4], avl[2][4];
#pragma unroll
  for (int mt = 0; mt < 2; ++mt)
#pragma unroll
    for (int r = 0; r < 4; ++r) {
      int a = mt * 16 + quad * 4 + r;
      c_reg[mt][r] = ctx[(size_t)(b * 64 + a0 + a) * 128 + wave * 16 + l16];
      avl[mt][r] = (cav[b * 64 + a0 + a] != 0) ? 1.f : 0.f;
    }

  // ---- persistent register-cached weights (step-invariant) ----
  const int wrow = wave * 16 + l16;
  short8 rIH[4][4], rHH[4][4];
#pragma unroll
  for (int kt = 0; kt < 4; ++kt)
#pragma unroll
    for (int g = 0; g < 4; ++g) {
      rIH[kt][g] = *(const short8*)(WIHO + ((g * 128 + wrow) * 128 + kt * 32 + quad * 8));
      rHH[kt][g] = *(const short8*)(WHH + ((g * 128 + wrow) * 128 + kt * 32 + quad * 8));
    }
  short8 rWQ3[2];
#pragma unroll
  for (int kt = 0; kt < 2; ++kt)
    rWQ3[kt] = *(const short8*)(WQ3 + (wrow * 64 + kt * 32 + quad * 8));
  float rB4[4];
#pragma unroll
  for (int g = 0; g < 4; ++g) rB4[g] = B4p[g * 128 + wrow];
  const float rBQ3 = BQ3S[wrow];
  const float rB2 = b2[(wave & 3) * 16 + l16];

  // ---- fused-P7/P0 per-thread constants + register state ----
  const int p7_o = tid >> 3, p7_sub = tid & 7;
  const int p7_a = p7_o >> 1, p7_oi = p7_o & 1;
  const float mylnb = lnb[p7_oi];
  float myst = cf[(size_t)(b * 64 + a0 + p7_a) * 2 + p7_oi];

  __syncthreads();

  // per-lane mask flags: bit i set when token i*16+l16 is NOT available.
  unsigned mflags = 0;
#pragma unroll
  for (int i = 0; i < 32; ++i)
    if (!s_maskb[i * 16 + l16]) mflags |= (1u << i);

  // ---- initial h1 from initial state (P0 stand-alone) ----
  {
    float other = __shfl_xor(myst, 8);
    float st0 = p7_oi ? other : myst;
    float st1 = p7_oi ? myst : other;
    int a = tid >> 4, n0 = (tid & 15) * 8;
    const float* wp = w1 + n0 * 2;
    const float* bp = b1 + n0;
    short8 v;
#pragma unroll
    for (int j = 0; j < 8; ++j) {
      float x = fmaf(wp[j * 2], st0, fmaf(wp[j * 2 + 1], st1, bp[j]));
      v[j] = (short)f2bf(fmaxf(x, 0.f));
    }
    *(short8*)(s_bufA + a * 136 + n0) = v;
  }
  __syncthreads();

#pragma unroll 1
  for (int t = 0; t < T; ++t) {
    // ---- P1: h2 = relu(h1 @ w2^T + b2)  M32 N64 K128 -> zone ----
    {
      int mt = wave >> 2, nt = wave & 3;
      f32x4 acc = splat4(rB2);
#pragma unroll
      for (int kt = 0; kt < 4; ++kt) {
        short8 a8 = *(const short8*)(s_bufA + (mt * 16 + l16) * 136 + kt * 32 + quad * 8);
        short8 b8 = *(const short8*)(W2 + ((nt * 16 + l16) * 128 + kt * 32 + quad * 8));
        acc = mfma_bf16(a8, b8, acc);
      }
#pragma unroll
      for (int r = 0; r < 4; ++r)
        s_h2[(mt * 16 + quad * 4 + r) * 72 + nt * 16 + l16] = f2bf(fmaxf(acc[r], 0.f));
    }
    __syncthreads();

    // ---- P3: q = h2 @ WQ3^T + bq3 -> fp8 in bufA bytes (h1 dead) ----
    // wave nt==h produces exactly head h's q-columns -> no barrier before P4.
    unsigned char* s_q8 = (unsigned char*)s_bufA;
    {
#pragma unroll
      for (int mt = 0; mt < 2; ++mt) {
        f32x4 acc = splat4(rBQ3);
#pragma unroll
        for (int kt = 0; kt < 2; ++kt) {
          short8 a8 = *(const short8*)(s_h2 + (mt * 16 + l16) * 72 + kt * 32 + quad * 8);
          acc = mfma_bf16(a8, rWQ3[kt], acc);
        }
#pragma unroll
        for (int r = 0; r < 4; ++r)
          s_q8[(mt * 16 + quad * 4 + r) * 136 + wave * 16 + l16] = f2fp8(acc[r]);
      }
    }
    __asm__ volatile("s_waitcnt lgkmcnt(0)" ::: "memory");
    __builtin_amdgcn_sched_barrier(0);

    // ---- P4: attention — swapped-operand MFMA, P in registers, prefetched ----
    {
      const int h = wave;
      const char* sKb = (const char*)smem;
      const char* sVrow = (const char*)(smem + 65536) + (h * 16 + l16) * 512;
      long qA[2];
#pragma unroll
      for (int mt = 0; mt < 2; ++mt)
        qA[mt] = (quad < 2)
                     ? *(const long*)(s_q8 + (mt * 16 + l16) * 136 + h * 16 + quad * 8)
                     : (quad == 2 ? 0xF8L : 0L);  // byte0 = fp8 -256
      const int koff = (h * 16 + quad * 8) ^ (l16 * 8);
      f32x4 O[2], L4[2];
      O[0] = zero4; O[1] = zero4; L4[0] = zero4; L4[1] = zero4;
      // prefetch chunk 0
      long vA_c = *(const long*)(sVrow + ((quad * 8) ^ (l16 * 8)));
      long kB_c0 = 0L, kB_c1 = 0L;
      if (quad < 2) {
        kB_c0 = *(const long*)(sKb + (size_t)l16 * 128 + koff);
        kB_c1 = *(const long*)(sKb + (size_t)(16 + l16) * 128 + koff);
      }
#pragma unroll 4
      for (int c = 0; c < 16; ++c) {
        long vA_n = 0L, kB_n0 = 0L, kB_n1 = 0L;
        if (c < 15) {
          vA_n = *(const long*)(sVrow + (((c + 1) * 32 + quad * 8) ^ (l16 * 8)));
          if (quad < 2) {
            kB_n0 = *(const long*)(sKb + (size_t)((c + 1) * 32 + l16) * 128 + koff);
            kB_n1 = *(const long*)(sKb + (size_t)((c + 1) * 32 + 16 + l16) * 128 + koff);
          }
        }
        long kB0 = kB_c0, kB1 = kB_c1;
        if (quad == 2) {
          kB0 = ((mflags >> (c * 2)) & 1u) ? 0x38L : 0L;      // fp8 1.0 flag
          kB1 = ((mflags >> (c * 2 + 1)) & 1u) ? 0x38L : 0L;
        }
        f32x4 S2[2][2];
        S2[0][0] = mfma_fp8(kB0, qA[0], zero4);
        S2[0][1] = mfma_fp8(kB0, qA[1], zero4);
        S2[1][0] = mfma_fp8(kB1, qA[0], zero4);
        S2[1][1] = mfma_fp8(kB1, qA[1], zero4);
#pragma unroll
        for (int mt = 0; mt < 2; ++mt) {
          unsigned w0 = (unsigned)__builtin_amdgcn_cvt_pk_fp8_f32(
              fexp2(S2[0][mt][0]), fexp2(S2[0][mt][1]), 0, false);
          w0 = (unsigned)__builtin_amdgcn_cvt_pk_fp8_f32(
              fexp2(S2[0][mt][2]), fexp2(S2[0][mt][3]), (int)w0, true);
          unsigned w1v = (unsigned)__builtin_amdgcn_cvt_pk_fp8_f32(
              fexp2(S2[1][mt][0]), fexp2(S2[1][mt][1]), 0, false);
          w1v = (unsigned)__builtin_amdgcn_cvt_pk_fp8_f32(
              fexp2(S2[1][mt][2]), fexp2(S2[1][mt][3]), (int)w1v, true);
          long pB = (long)(((unsigned long long)w1v << 32) | (unsigned long long)w0);
          O[mt] = mfma_fp8(vA_c, pB, O[mt]);     // O^T: rows d-local, cols a
          L4[mt] = mfma_fp8(kOnes, pB, L4[mt]);
        }
        vA_c = vA_n; kB_c0 = kB_n0; kB_c1 = kB_n1;
      }
      // o -> bufB; O^T lane layout: d = h*16+quad*4+r, a = mt*16+l16
#pragma unroll
      for (int mt = 0; mt < 2; ++mt) {
        unsigned long long ow = 0;
#pragma unroll
        for (int r = 0; r < 4; ++r) {
          float o_r = O[mt][r] * frcp(L4[mt][r]);
          ow |= (unsigned long long)f2bf(o_r) << (16 * r);
        }
        *(unsigned long long*)(s_bufB + (mt * 16 + l16) * 136 + h * 16 + quad * 4) = ow;
      }
    }
    __syncthreads();

    // ---- P6: LSTM gates (x-part folded through WO; weights in regs) ----
    {
      const int ni = wave;
      f32x4 gi[2], gf[2], gg[2], go[2];
#pragma unroll
      for (int mt = 0; mt < 2; ++mt) {
        gi[mt] = splat4(rB4[0]);
        gf[mt] = splat4(rB4[1]);
        gg[mt] = splat4(rB4[2]);
        go[mt] = splat4(rB4[3]);
      }
#pragma unroll
      for (int kt = 0; kt < 4; ++kt)
#pragma unroll
        for (int mt = 0; mt < 2; ++mt) {
          short8 a8 = *(const short8*)(s_bufB + (mt * 16 + l16) * 136 + kt * 32 + quad * 8);
          gi[mt] = mfma_bf16(a8, rIH[kt][0], gi[mt]);
          gf[mt] = mfma_bf16(a8, rIH[kt][1], gf[mt]);
          gg[mt] = mfma_bf16(a8, rIH[kt][2], gg[mt]);
          go[mt] = mfma_bf16(a8, rIH[kt][3], go[mt]);
        }
#pragma unroll
      for (int kt = 0; kt < 4; ++kt)
#pragma unroll
        for (int mt = 0; mt < 2; ++mt) {
          short8 a8 = *(const short8*)(s_h + (mt * 16 + l16) * 136 + kt * 32 + quad * 8);
          gi[mt] = mfma_bf16(a8, rHH[kt][0], gi[mt]);
          gf[mt] = mfma_bf16(a8, rHH[kt][1], gf[mt]);
          gg[mt] = mfma_bf16(a8, rHH[kt][2], gg[mt]);
          go[mt] = mfma_bf16(a8, rHH[kt][3], go[mt]);
        }
      float hnew[2][4];
#pragma unroll
      for (int mt = 0; mt < 2; ++mt)
#pragma unroll
        for (int r = 0; r < 4; ++r) {
          float iv = sigm(gi[mt][r]);
          float fv = sigm(gf[mt][r]);
          float gv = tanh_f(gg[mt][r]);
          float ov = sigm(go[mt][r]);
          float cn = fmaf(fv, c_reg[mt][r], iv * gv);
          float hv = ov * tanh_f(cn);
          int arow = mt * 16 + quad * 4 + r;
          float av = avl[mt][r];
          union { unsigned int u; float f; } ho;
          ho.u = ((unsigned int)s_h[arow * 136 + ni * 16 + l16]) << 16;
          c_reg[mt][r] = av * cn + (1.f - av) * c_reg[mt][r];
          hnew[mt][r] = av * hv + (1.f - av) * ho.f;
        }
      __syncthreads();  // all h reads (incl. MFMA A-frags) done before overwrite
#pragma unroll
      for (int mt = 0; mt < 2; ++mt)
#pragma unroll
        for (int r = 0; r < 4; ++r) {
          int arow = mt * 16 + quad * 4 + r;
          s_h[arow * 136 + ni * 16 + l16] = f2bf(hnew[mt][r]);
        }
    }
    __syncthreads();

    // ---- P7+P0 fused: state += h @ lin_w^T + lin_b; emit; next h1 ----
    {
      const unsigned short* hp = s_h + p7_a * 136 + p7_sub * 16;
      const float* lw = lnw + p7_oi * 128 + p7_sub * 16;
      short8 h0 = *(const short8*)hp;
      short8 h1 = *(const short8*)(hp + 8);
      float acc = 0.f;
#pragma unroll
      for (int k = 0; k < 8; ++k) {
        union { unsigned int u; float f; } hv;
        hv.u = ((unsigned int)(unsigned short)h0[k]) << 16;
        acc = fmaf(hv.f, lw[k], acc);
      }
#pragma unroll
      for (int k = 0; k < 8; ++k) {
        union { unsigned int u; float f; } hv;
        hv.u = ((unsigned int)(unsigned short)h1[k]) << 16;
        acc = fmaf(hv.f, lw[8 + k], acc);
      }
      acc += __shfl_xor(acc, 4);
      acc += __shfl_xor(acc, 2);
      acc += __shfl_xor(acc, 1);
      float ns = myst + acc + mylnb;
      myst = ns;
      if (p7_sub == 0)
        out[((size_t)(b * 64 + a0 + p7_a) * T + t) * 2 + p7_oi] = ns;
      // P0: h1(t+1) = relu(state @ w1^T + b1) -> bufA
      float other = __shfl_xor(ns, 8);
      float st0 = p7_oi ? other : ns;
      float st1 = p7_oi ? ns : other;
      int a = tid >> 4, n0 = (tid & 15) * 8;
      const float* wp = w1 + n0 * 2;
      const float* bp = b1 + n0;
      short8 v;
#pragma unroll
      for (int j = 0; j < 8; ++j) {
        float x = fmaf(wp[j * 2], st0, fmaf(wp[j * 2 + 1], st1, bp[j]));
        v[j] = (short)f2bf(fmaxf(x, 0.f));
      }
      *(short8*)(s_bufA + a * 136 + n0) = v;
    }
    __syncthreads();
  }
}

// ---------------------------------------------------------------- launch ----
extern "C" void kernel_launch(void* const* d_in, const int* in_sizes, int n_in,
                              void* d_out, int out_size, void* d_ws, size_t ws_size,
                              hipStream_t stream) {
  (void)in_sizes; (void)n_in; (void)out_size; (void)ws_size;
  const float* cf = (const float*)d_in[0];
  const int* cav = (const int*)d_in[1];
  const float* hid = (const float*)d_in[2];
  const float* ctx = (const float*)d_in[3];
  const float* emb = (const float*)d_in[4];
  const int* mav = (const int*)d_in[5];
  const int* ntp = (const int*)d_in[6];
  const float* w1 = (const float*)d_in[7];
  const float* b1 = (const float*)d_in[8];
  const float* w2 = (const float*)d_in[9];
  const float* b2 = (const float*)d_in[10];
  const float* w3 = (const float*)d_in[11];
  const float* b3 = (const float*)d_in[12];
  const float* wq = (const float*)d_in[13];
  const float* bq = (const float*)d_in[14];
  const float* wk = (const float*)d_in[15];
  const float* bk = (const float*)d_in[16];
  const float* wv = (const float*)d_in[17];
  const float* bv = (const float*)d_in[18];
  const float* wo = (const float*)d_in[19];
  const float* bo = (const float*)d_in[20];
  const float* wih = (const float*)d_in[21];  // w_ih
  const float* whh = (const float*)d_in[22];  // w_hh
  const float* bih = (const float*)d_in[23];  // b_ih
  const float* bhh = (const float*)d_in[24];  // b_hh
  const float* lnw = (const float*)d_in[25];
  const float* lnb = (const float*)d_in[26];

  char* ws = (char*)d_ws;
  unsigned char* K8 = (unsigned char*)(ws + 0);         // 8,388,608
  unsigned char* V8 = (unsigned char*)(ws + 8388608);   // 8,388,608
  unsigned short* W2s = (unsigned short*)(ws + 16777216);   // 16,384 B
  unsigned short* WQ3s = (unsigned short*)(ws + 16793600);  // 16,384 B
  unsigned short* WIHOs = (unsigned short*)(ws + 16809984); // 131,072 B
  unsigned short* WHHs = (unsigned short*)(ws + 16941056);  // 131,072 B
  float* B4p = (float*)(ws + 17072128);                     // 2,048 B
  float* BQ3S = (float*)(ws + 17074176);                    // 512 B

  (void)hipFuncSetAttribute((const void*)kv_kernel,
                            hipFuncAttributeMaxDynamicSharedMemorySize, 99072);
  (void)hipFuncSetAttribute((const void*)decoder_kernel,
                            hipFuncAttributeMaxDynamicSharedMemorySize, 162560);

  convert_kernel<<<288, 256, 0, stream>>>(w2, whh, W2s, WHHs);
  fold_wiho_kernel<<<256, 256, 0, stream>>>(wih, wo, WIHOs);
  fold_wq3b_kernel<<<35, 256, 0, stream>>>(wq, w3, b3, bq, wih, bo, bih, bhh,
                                           WQ3s, B4p, BQ3S);
  kv_kernel<<<1024, 256, 99072, stream>>>(emb, wk, bk, wv, bv, K8, V8);
  decoder_kernel<<<256, 512, 162560, stream>>>(
      cf, cav, hid, ctx, mav, ntp, w1, b1, b2, K8, V8, W2s, WQ3s, WIHOs, WHHs,
      B4p, BQ3S, lnw, lnb, (float*)d_out);
}